// Round 6
// baseline (318.702 us; speedup 1.0000x reference)
//
#include <hip/hip_runtime.h>
#include <math.h>

#define C_LEN 2048
#define HALF  1024
#define OUTD  1536
#define NPIX  32768

#define SCHED_FENCE() __builtin_amdgcn_sched_barrier(0)

// ======================= uv + twiddle-table precompute ======================
__device__ __forceinline__ int SWZ(int idx) { return idx ^ ((idx >> 5) & 31); }

template<int DIR>
__device__ void fft2048(float* r0, float* i0, float* r1, float* i1, int t) {
    float *sr = r0, *si = i0, *dr = r1, *di = i1;
    const float TW = (float)DIR * 6.283185307179586f / 2048.0f;
    const float FD = (float)DIR;
    __syncthreads();
    #pragma unroll
    for (int b = 0; b < 4; ++b) {
        int t2 = t + b * 256;
        float ar = sr[SWZ(t2)],        ai = si[SWZ(t2)];
        float br = sr[SWZ(t2 + 1024)], bi = si[SWZ(t2 + 1024)];
        float sn, cs;
        sincosf(TW * (float)t2, &sn, &cs);
        float vr = ar - br, vi = ai - bi;
        int w0 = 2 * t2;
        dr[SWZ(w0)]     = ar + br;
        di[SWZ(w0)]     = ai + bi;
        dr[SWZ(w0 + 1)] = cs * vr - sn * vi;
        di[SWZ(w0 + 1)] = cs * vi + sn * vr;
    }
    { float* tp; tp = sr; sr = dr; dr = tp; tp = si; si = di; di = tp; }
    #pragma unroll
    for (int m = 2; m <= 512; m *= 4) {
        __syncthreads();
        #pragma unroll
        for (int b = 0; b < 2; ++b) {
            int t2 = t + b * 256;
            int jm = t2 & ~(m - 1);
            float a0r = sr[SWZ(t2)],        a0i = si[SWZ(t2)];
            float a1r = sr[SWZ(t2 + 512)],  a1i = si[SWZ(t2 + 512)];
            float a2r = sr[SWZ(t2 + 1024)], a2i = si[SWZ(t2 + 1024)];
            float a3r = sr[SWZ(t2 + 1536)], a3i = si[SWZ(t2 + 1536)];
            float s0r = a0r + a2r, s0i = a0i + a2i;
            float d0r = a0r - a2r, d0i = a0i - a2i;
            float s1r = a1r + a3r, s1i = a1i + a3i;
            float d1r = a1r - a3r, d1i = a1i - a3i;
            float A0r = s0r + s1r, A0i = s0i + s1i;
            float A2r = s0r - s1r, A2i = s0i - s1i;
            float A1r = d0r - FD * d1i, A1i = d0i + FD * d1r;
            float A3r = d0r + FD * d1i, A3i = d0i - FD * d1r;
            float s1w, c1w;
            sincosf(TW * (float)jm, &s1w, &c1w);
            float c2w = c1w * c1w - s1w * s1w, s2w = 2.0f * c1w * s1w;
            float c3w = c1w * c2w - s1w * s2w, s3w = c1w * s2w + s1w * c2w;
            int wb = t2 + 3 * jm;
            dr[SWZ(wb)]         = A0r;
            di[SWZ(wb)]         = A0i;
            dr[SWZ(wb + m)]     = c1w * A1r - s1w * A1i;
            di[SWZ(wb + m)]     = c1w * A1i + s1w * A1r;
            dr[SWZ(wb + 2 * m)] = c2w * A2r - s2w * A2i;
            di[SWZ(wb + 2 * m)] = c2w * A2i + s2w * A2r;
            dr[SWZ(wb + 3 * m)] = c3w * A3r - s3w * A3i;
            di[SWZ(wb + 3 * m)] = c3w * A3i + s3w * A3r;
        }
        { float* tp; tp = sr; sr = dr; dr = tp; tp = si; si = di; di = tp; }
    }
    __syncthreads();
}

__global__ __launch_bounds__(256)
void uv_kernel(const float* __restrict__ w1, const float* __restrict__ w2,
               float4* __restrict__ uv, float2* __restrict__ tab1T,
               float2* __restrict__ tab2T) {
    __shared__ float r0[C_LEN], i0[C_LEN], r1[C_LEN], i1[C_LEN];
    int t = threadIdx.x;
    #pragma unroll
    for (int k = 0; k < 8; ++k) {
        int e = t + k * 256;
        r0[SWZ(e)] = w1[e] * w2[e];
        i0[SWZ(e)] = 0.0f;
    }
    fft2048<-1>(r0, i0, r1, i1, t);
    #pragma unroll
    for (int b = 0; b < 4; ++b) {
        int k = t + b * 256;
        float w1r = r0[SWZ(k)],        w1i = i0[SWZ(k)];
        float w2r = r0[SWZ(k + 1024)], w2i = i0[SWZ(k + 1024)];
        float Sr = (w1r + w2r) * (1.0f / 4096.0f);
        float Si = (w1i + w2i) * (1.0f / 4096.0f);
        float Dr = (w1r - w2r) * (1.0f / 4096.0f);
        float Di = (w1i - w2i) * (1.0f / 4096.0f);
        float sn, cs;
        sincosf((6.283185307179586f / 2048.0f) * (float)k, &sn, &cs);
        float Er = cs * Dr - sn * Di, Ei = cs * Di + sn * Dr;
        float Fr = cs * Dr + sn * Di, Fi = cs * Di - sn * Dr;
        uv[k] = make_float4(Sr - Ei, Si + Er, Sr + Fi, Si - Fr);
    }
    // Transposed twiddle tables (forward sign; inverse conjugates in-reg):
    // tab1T[c*64 + t] = exp(-2*pi*i*t*c/1024), c in [0,16), t in [0,64)
    #pragma unroll
    for (int b = 0; b < 4; ++b) {
        int e = t + b * 256;
        int c = e >> 6, lane = e & 63;
        float sn, cs;
        sincosf((-6.283185307179586f / 1024.0f) * (float)(lane * c), &sn, &cs);
        tab1T[e] = make_float2(cs, sn);
    }
    // tab2T[m*4 + f] = exp(-2*pi*i*f*m/64), m in [0,16), f in [0,4)
    if (t < 64) {
        int m = t >> 2, f = t & 3;
        float sn, cs;
        sincosf((-6.283185307179586f / 64.0f) * (float)(f * m), &sn, &cs);
        tab2T[t] = make_float2(cs, sn);
    }
}

// ======================= in-place register FFT16 ============================
__device__ __forceinline__ void cm(float& or_, float& oi_, float ar, float ai,
                                   float br, float bi) {
    or_ = ar * br - ai * bi;
    oi_ = ar * bi + ai * br;
}

// In-place 16-pt DFT (sign S). Output digit-swapped:
//   slot[4*(k&3) + (k>>2)] = X[k],  X[k] = sum_n x[n] e^{S*2*pi*i*n*k/16}
template<int S>
__device__ __forceinline__ void fft16_ip(float* xr, float* xi) {
    const float FS = (float)S;
    const float C1 = 0.9238795325112867f;
    const float S1 = 0.3826834323650898f;
    const float R2 = 0.7071067811865476f;
    #pragma unroll
    for (int n0 = 0; n0 < 4; ++n0) {
        float a0r = xr[n0],      a0i = xi[n0];
        float a1r = xr[n0 + 4],  a1i = xi[n0 + 4];
        float a2r = xr[n0 + 8],  a2i = xi[n0 + 8];
        float a3r = xr[n0 + 12], a3i = xi[n0 + 12];
        float t0r = a0r + a2r, t0i = a0i + a2i;
        float t1r = a0r - a2r, t1i = a0i - a2i;
        float t2r = a1r + a3r, t2i = a1i + a3i;
        float t3r = a1r - a3r, t3i = a1i - a3i;
        float y1r = t1r - FS * t3i, y1i = t1i + FS * t3r;
        float y2r = t0r - t2r,      y2i = t0i - t2i;
        float y3r = t1r + FS * t3i, y3i = t1i - FS * t3r;
        xr[n0] = t0r + t2r;  xi[n0] = t0i + t2i;
        if (n0 == 0) {
            xr[4]  = y1r; xi[4]  = y1i;
            xr[8]  = y2r; xi[8]  = y2i;
            xr[12] = y3r; xi[12] = y3i;
        } else if (n0 == 1) {
            cm(xr[5],  xi[5],  y1r, y1i, C1,  FS * S1);
            cm(xr[9],  xi[9],  y2r, y2i, R2,  FS * R2);
            cm(xr[13], xi[13], y3r, y3i, S1,  FS * C1);
        } else if (n0 == 2) {
            cm(xr[6],  xi[6],  y1r, y1i, R2,  FS * R2);
            xr[10] = -FS * y2i;  xi[10] = FS * y2r;
            cm(xr[14], xi[14], y3r, y3i, -R2, FS * R2);
        } else {
            cm(xr[7],  xi[7],  y1r, y1i, S1,  FS * C1);
            cm(xr[11], xi[11], y2r, y2i, -R2, FS * R2);
            cm(xr[15], xi[15], y3r, y3i, -C1, -FS * S1);
        }
    }
    #pragma unroll
    for (int k0 = 0; k0 < 4; ++k0) {
        float b0r = xr[4 * k0],     b0i = xi[4 * k0];
        float b1r = xr[4 * k0 + 1], b1i = xi[4 * k0 + 1];
        float b2r = xr[4 * k0 + 2], b2i = xi[4 * k0 + 2];
        float b3r = xr[4 * k0 + 3], b3i = xi[4 * k0 + 3];
        float t0r = b0r + b2r, t0i = b0i + b2i;
        float t1r = b0r - b2r, t1i = b0i - b2i;
        float t2r = b1r + b3r, t2i = b1i + b3i;
        float t3r = b1r - b3r, t3i = b1i - b3i;
        xr[4 * k0]     = t0r + t2r;      xi[4 * k0]     = t0i + t2i;
        xr[4 * k0 + 1] = t1r - FS * t3i; xi[4 * k0 + 1] = t1i + FS * t3r;
        xr[4 * k0 + 2] = t0r - t2r;      xi[4 * k0 + 2] = t0i - t2i;
        xr[4 * k0 + 3] = t1r + FS * t3i; xi[4 * k0 + 3] = t1i - FS * t3r;
    }
}

// Table twiddle + transposed LDS store. Lane reads its 16 twiddles from a
// TRANSPOSED global table (tabT[c*stride + lane] -> coalesced 512B rows,
// L1-resident). CONJ=1 conjugates (inverse pass). Reads digit-swapped slot.
template<int CONJ>
__device__ __forceinline__ void tw_store_tab(const float* vr, const float* vi,
                                             float2* row, int xorv,
                                             const float2* __restrict__ tabT,
                                             int stride, int lane) {
    #pragma unroll
    for (int c = 0; c < 16; ++c) {
        float2 w = tabT[c * stride + lane];
        float wr = w.x;
        float wi = CONJ ? -w.y : w.y;
        int p = ((c & 3) << 2) | (c >> 2);
        float x = vr[p] * wr - vi[p] * wi;
        float y = vr[p] * wi + vi[p] * wr;
        row[c ^ xorv] = make_float2(x, y);
    }
}

// ======================= main kernel: wave per pixel, 4 waves/block =========
// R4 skeleton (barriers = scheduling fences, 56-VGPR regime) + global
// twiddle tables. sched_barrier(0) at phase boundaries pins program order
// so the table loads cannot be hoisted across phases (R5's VGPR blowup).
__global__ __launch_bounds__(256, 4)
void conv256(const float* __restrict__ x, const float4* __restrict__ uv,
             const float2* __restrict__ tab1T, const float2* __restrict__ tab2T,
             float2* __restrict__ out) {
    __shared__ float2 ldsAll[4 * HALF];
    const int tid = threadIdx.x;
    const int t   = tid & 63;
    const int wid = tid >> 6;
    float2* lds = ldsAll + (wid << 10);
    const size_t pix = ((size_t)blockIdx.x << 2) + wid;
    const float2* xp = reinterpret_cast<const float2*>(x) + pix * (size_t)HALF;

    float vr[16], vi[16];
    #pragma unroll
    for (int a = 0; a < 16; ++a) {
        float2 z = xp[(a << 6) + t];
        vr[a] = z.x; vi[a] = z.y;
    }

    // ---------------- forward ----------------
    fft16_ip<-1>(vr, vi);
    SCHED_FENCE();
    tw_store_tab<0>(vr, vi, lds + (t << 4), t & 15, tab1T, 64, t);   // T1 w
    SCHED_FENCE();
    __syncthreads();
    {
        const int f = t & 3, c = t >> 2;
        #pragma unroll
        for (int e = 0; e < 16; ++e) {                               // T1 r
            int row = (e << 2) + f;
            float2 z = lds[(row << 4) + (c ^ (row & 15))];
            vr[e] = z.x; vi[e] = z.y;
        }
        __syncthreads();
        fft16_ip<-1>(vr, vi);
        SCHED_FENCE();
        tw_store_tab<0>(vr, vi, lds + (t << 4), c, tab2T, 4, f);     // T2 w
        SCHED_FENCE();
    }
    __syncthreads();
    {
        const int q = t & 3, c = t >> 2;
        float dr[16], di[16];
        #pragma unroll
        for (int f = 0; f < 4; ++f) {
            #pragma unroll
            for (int s = 0; s < 4; ++s) {                            // T2 r
                int wrow = (c << 2) + f;
                float2 z = lds[(wrow << 4) + (((q << 2) + s) ^ c)];
                dr[f * 4 + s] = z.x; di[f * 4 + s] = z.y;
            }
        }
        __syncthreads();
        #pragma unroll
        for (int s = 0; s < 4; ++s) {                                // FFT4 f
            float ar = dr[0 + s],  ai = di[0 + s];
            float br = dr[4 + s],  bi = di[4 + s];
            float cr = dr[8 + s],  ci = di[8 + s];
            float er = dr[12 + s], ei = di[12 + s];
            float t0r = ar + cr, t0i = ai + ci;
            float t1r = ar - cr, t1i = ai - ci;
            float t2r = br + er, t2i = bi + ei;
            float t3r = br - er, t3i = bi - ei;
            int kb = c + (((q << 2) + s) << 4);
            lds[kb]       = make_float2(t0r + t2r, t0i + t2i);       // p=0
            lds[kb + 256] = make_float2(t1r + t3i, t1i - t3r);       // p=1
            lds[kb + 512] = make_float2(t0r - t2r, t0i - t2i);       // p=2
            lds[kb + 768] = make_float2(t1r - t3i, t1i + t3r);       // p=3
        }
    }
    SCHED_FENCE();
    __syncthreads();

    // ------------- middle (rfft unpack * Wf * repack) ------------
    #pragma unroll
    for (int a = 0; a < 16; ++a) {
        int k = (a << 6) + t;
        float2 Za = lds[k];
        float2 Zm = lds[(HALF - k) & (HALF - 1)];
        float4 u  = uv[k];
        float Ar = Za.x + Zm.x, Ai = Za.y - Zm.y;
        float Br = Za.x - Zm.x, Bi = Za.y + Zm.y;
        vr[a] = Ar * u.x - Ai * u.y + Br * u.z - Bi * u.w;
        vi[a] = Ar * u.y + Ai * u.x + Br * u.w + Bi * u.z;
    }
    SCHED_FENCE();
    __syncthreads();

    // ---------------- inverse ----------------
    fft16_ip<1>(vr, vi);
    SCHED_FENCE();
    tw_store_tab<1>(vr, vi, lds + (t << 4), t & 15, tab1T, 64, t);   // T4 w
    SCHED_FENCE();
    __syncthreads();
    {
        const int f = t & 3, c = t >> 2;
        #pragma unroll
        for (int e = 0; e < 16; ++e) {                               // T4 r
            int row = (e << 2) + f;
            float2 z = lds[(row << 4) + (c ^ (row & 15))];
            vr[e] = z.x; vi[e] = z.y;
        }
        __syncthreads();
        fft16_ip<1>(vr, vi);
        SCHED_FENCE();
        tw_store_tab<1>(vr, vi, lds + (t << 4), c, tab2T, 4, f);     // T5 w
        SCHED_FENCE();
    }
    __syncthreads();
    {
        const int q = t & 3, c = t >> 2;
        float dr[16], di[16];
        #pragma unroll
        for (int f = 0; f < 4; ++f) {
            #pragma unroll
            for (int s = 0; s < 4; ++s) {                            // T5 r
                int wrow = (c << 2) + f;
                float2 z = lds[(wrow << 4) + (((q << 2) + s) ^ c)];
                dr[f * 4 + s] = z.x; di[f * 4 + s] = z.y;
            }
        }
        float2* op = out + pix * (size_t)(OUTD / 2);
        #pragma unroll
        for (int s = 0; s < 4; ++s) {                                // FFT4 i
            float ar = dr[0 + s],  ai = di[0 + s];
            float br = dr[4 + s],  bi = di[4 + s];
            float cr = dr[8 + s],  ci = di[8 + s];
            float er = dr[12 + s], ei = di[12 + s];
            float t0r = ar + cr, t0i = ai + ci;
            float t1r = ar - cr, t1i = ai - ci;
            float t2r = br + er, t2i = bi + ei;
            float t3r = br - er, t3i = bi - ei;
            int nb = c + (((q << 2) + s) << 4);
            op[nb]       = make_float2(t0r + t2r, t0i + t2i);        // p=0
            op[nb + 256] = make_float2(t1r - t3i, t1i + t3r);        // p=1
            op[nb + 512] = make_float2(t0r - t2r, t0i - t2i);        // p=2
            // p=3 (n >= 768) not stored
        }
    }
}

extern "C" void kernel_launch(void* const* d_in, const int* in_sizes, int n_in,
                              void* d_out, int out_size, void* d_ws, size_t ws_size,
                              hipStream_t stream) {
    const float* x  = (const float*)d_in[0];
    const float* w1 = (const float*)d_in[1];
    const float* w2 = (const float*)d_in[2];
    float2* out = (float2*)d_out;
    char* ws = (char*)d_ws;
    float4* uv    = (float4*)ws;                    // 16 KB
    float2* tab1T = (float2*)(ws + 16384);          // 8 KB
    float2* tab2T = (float2*)(ws + 16384 + 8192);   // 512 B

    hipLaunchKernelGGL(uv_kernel, dim3(1), dim3(256), 0, stream,
                       w1, w2, uv, tab1T, tab2T);
    hipLaunchKernelGGL(conv256, dim3(NPIX / 4), dim3(256), 0, stream,
                       x, uv, tab1T, tab2T, out);
}

// Round 7
// 138.043 us; speedup vs baseline: 2.3087x; 2.3087x over previous
//
#include <hip/hip_runtime.h>
#include <math.h>

#define C_LEN 2048
#define HALF  1024
#define OUTD  1536
#define NPIX  32768

// ======================= uv precompute (unchanged, verified) ================
__device__ __forceinline__ int SWZ(int idx) { return idx ^ ((idx >> 5) & 31); }

template<int DIR>
__device__ void fft2048(float* r0, float* i0, float* r1, float* i1, int t) {
    float *sr = r0, *si = i0, *dr = r1, *di = i1;
    const float TW = (float)DIR * 6.283185307179586f / 2048.0f;
    const float FD = (float)DIR;
    __syncthreads();
    #pragma unroll
    for (int b = 0; b < 4; ++b) {
        int t2 = t + b * 256;
        float ar = sr[SWZ(t2)],        ai = si[SWZ(t2)];
        float br = sr[SWZ(t2 + 1024)], bi = si[SWZ(t2 + 1024)];
        float sn, cs;
        sincosf(TW * (float)t2, &sn, &cs);
        float vr = ar - br, vi = ai - bi;
        int w0 = 2 * t2;
        dr[SWZ(w0)]     = ar + br;
        di[SWZ(w0)]     = ai + bi;
        dr[SWZ(w0 + 1)] = cs * vr - sn * vi;
        di[SWZ(w0 + 1)] = cs * vi + sn * vr;
    }
    { float* tp; tp = sr; sr = dr; dr = tp; tp = si; si = di; di = tp; }
    #pragma unroll
    for (int m = 2; m <= 512; m *= 4) {
        __syncthreads();
        #pragma unroll
        for (int b = 0; b < 2; ++b) {
            int t2 = t + b * 256;
            int jm = t2 & ~(m - 1);
            float a0r = sr[SWZ(t2)],        a0i = si[SWZ(t2)];
            float a1r = sr[SWZ(t2 + 512)],  a1i = si[SWZ(t2 + 512)];
            float a2r = sr[SWZ(t2 + 1024)], a2i = si[SWZ(t2 + 1024)];
            float a3r = sr[SWZ(t2 + 1536)], a3i = si[SWZ(t2 + 1536)];
            float s0r = a0r + a2r, s0i = a0i + a2i;
            float d0r = a0r - a2r, d0i = a0i - a2i;
            float s1r = a1r + a3r, s1i = a1i + a3i;
            float d1r = a1r - a3r, d1i = a1i - a3i;
            float A0r = s0r + s1r, A0i = s0i + s1i;
            float A2r = s0r - s1r, A2i = s0i - s1i;
            float A1r = d0r - FD * d1i, A1i = d0i + FD * d1r;
            float A3r = d0r + FD * d1i, A3i = d0i - FD * d1r;
            float s1w, c1w;
            sincosf(TW * (float)jm, &s1w, &c1w);
            float c2w = c1w * c1w - s1w * s1w, s2w = 2.0f * c1w * s1w;
            float c3w = c1w * c2w - s1w * s2w, s3w = c1w * s2w + s1w * c2w;
            int wb = t2 + 3 * jm;
            dr[SWZ(wb)]         = A0r;
            di[SWZ(wb)]         = A0i;
            dr[SWZ(wb + m)]     = c1w * A1r - s1w * A1i;
            di[SWZ(wb + m)]     = c1w * A1i + s1w * A1r;
            dr[SWZ(wb + 2 * m)] = c2w * A2r - s2w * A2i;
            di[SWZ(wb + 2 * m)] = c2w * A2i + s2w * A2r;
            dr[SWZ(wb + 3 * m)] = c3w * A3r - s3w * A3i;
            di[SWZ(wb + 3 * m)] = c3w * A3i + s3w * A3r;
        }
        { float* tp; tp = sr; sr = dr; dr = tp; tp = si; si = di; di = tp; }
    }
    __syncthreads();
}

__global__ __launch_bounds__(256)
void uv_kernel(const float* __restrict__ w1, const float* __restrict__ w2,
               float4* __restrict__ uv) {
    __shared__ float r0[C_LEN], i0[C_LEN], r1[C_LEN], i1[C_LEN];
    int t = threadIdx.x;
    #pragma unroll
    for (int k = 0; k < 8; ++k) {
        int e = t + k * 256;
        r0[SWZ(e)] = w1[e] * w2[e];
        i0[SWZ(e)] = 0.0f;
    }
    fft2048<-1>(r0, i0, r1, i1, t);
    #pragma unroll
    for (int b = 0; b < 4; ++b) {
        int k = t + b * 256;
        float w1r = r0[SWZ(k)],        w1i = i0[SWZ(k)];
        float w2r = r0[SWZ(k + 1024)], w2i = i0[SWZ(k + 1024)];
        float Sr = (w1r + w2r) * (1.0f / 4096.0f);
        float Si = (w1i + w2i) * (1.0f / 4096.0f);
        float Dr = (w1r - w2r) * (1.0f / 4096.0f);
        float Di = (w1i - w2i) * (1.0f / 4096.0f);
        float sn, cs;
        sincosf((6.283185307179586f / 2048.0f) * (float)k, &sn, &cs);
        float Er = cs * Dr - sn * Di, Ei = cs * Di + sn * Dr;
        float Fr = cs * Dr + sn * Di, Fi = cs * Di - sn * Dr;
        uv[k] = make_float4(Sr - Ei, Si + Er, Sr + Fi, Si - Fr);
    }
}

// ======================= in-place register FFT16 ============================
__device__ __forceinline__ void cm(float& or_, float& oi_, float ar, float ai,
                                   float br, float bi) {
    or_ = ar * br - ai * bi;
    oi_ = ar * bi + ai * br;
}

// In-place 16-pt DFT (sign S). Output digit-swapped:
//   slot[4*(k&3) + (k>>2)] = X[k],  X[k] = sum_n x[n] e^{S*2*pi*i*n*k/16}
template<int S>
__device__ __forceinline__ void fft16_ip(float* xr, float* xi) {
    const float FS = (float)S;
    const float C1 = 0.9238795325112867f;
    const float S1 = 0.3826834323650898f;
    const float R2 = 0.7071067811865476f;
    #pragma unroll
    for (int n0 = 0; n0 < 4; ++n0) {
        float a0r = xr[n0],      a0i = xi[n0];
        float a1r = xr[n0 + 4],  a1i = xi[n0 + 4];
        float a2r = xr[n0 + 8],  a2i = xi[n0 + 8];
        float a3r = xr[n0 + 12], a3i = xi[n0 + 12];
        float t0r = a0r + a2r, t0i = a0i + a2i;
        float t1r = a0r - a2r, t1i = a0i - a2i;
        float t2r = a1r + a3r, t2i = a1i + a3i;
        float t3r = a1r - a3r, t3i = a1i - a3i;
        float y1r = t1r - FS * t3i, y1i = t1i + FS * t3r;
        float y2r = t0r - t2r,      y2i = t0i - t2i;
        float y3r = t1r + FS * t3i, y3i = t1i - FS * t3r;
        xr[n0] = t0r + t2r;  xi[n0] = t0i + t2i;
        if (n0 == 0) {
            xr[4]  = y1r; xi[4]  = y1i;
            xr[8]  = y2r; xi[8]  = y2i;
            xr[12] = y3r; xi[12] = y3i;
        } else if (n0 == 1) {
            cm(xr[5],  xi[5],  y1r, y1i, C1,  FS * S1);
            cm(xr[9],  xi[9],  y2r, y2i, R2,  FS * R2);
            cm(xr[13], xi[13], y3r, y3i, S1,  FS * C1);
        } else if (n0 == 2) {
            cm(xr[6],  xi[6],  y1r, y1i, R2,  FS * R2);
            xr[10] = -FS * y2i;  xi[10] = FS * y2r;
            cm(xr[14], xi[14], y3r, y3i, -R2, FS * R2);
        } else {
            cm(xr[7],  xi[7],  y1r, y1i, S1,  FS * C1);
            cm(xr[11], xi[11], y2r, y2i, -R2, FS * R2);
            cm(xr[15], xi[15], y3r, y3i, -C1, -FS * S1);
        }
    }
    #pragma unroll
    for (int k0 = 0; k0 < 4; ++k0) {
        float b0r = xr[4 * k0],     b0i = xi[4 * k0];
        float b1r = xr[4 * k0 + 1], b1i = xi[4 * k0 + 1];
        float b2r = xr[4 * k0 + 2], b2i = xi[4 * k0 + 2];
        float b3r = xr[4 * k0 + 3], b3i = xi[4 * k0 + 3];
        float t0r = b0r + b2r, t0i = b0i + b2i;
        float t1r = b0r - b2r, t1i = b0i - b2i;
        float t2r = b1r + b3r, t2i = b1i + b3i;
        float t3r = b1r - b3r, t3i = b1i - b3i;
        xr[4 * k0]     = t0r + t2r;      xi[4 * k0]     = t0i + t2i;
        xr[4 * k0 + 1] = t1r - FS * t3i; xi[4 * k0 + 1] = t1i + FS * t3r;
        xr[4 * k0 + 2] = t0r - t2r;      xi[4 * k0 + 2] = t0i - t2i;
        xr[4 * k0 + 3] = t1r + FS * t3i; xi[4 * k0 + 3] = t1i - FS * t3r;
    }
}

// Fused twiddle (w^c = e^{i*c*th}) + transposed LDS store.
// Reads logical element c from digit-swapped slot, writes row[c ^ xorv].
__device__ __forceinline__ void tw_store(const float* vr, const float* vi,
                                         float2* row, int xorv, float th) {
    float bs, bc;
    __sincosf(th, &bs, &bc);
    float aR[4], aI[4], bR[4], bI[4];
    aR[0] = 1.f; aI[0] = 0.f;
    aR[1] = bc;  aI[1] = bs;
    aR[2] = bc * bc - bs * bs;          aI[2] = 2.f * bc * bs;
    aR[3] = aR[2] * bc - aI[2] * bs;    aI[3] = aR[2] * bs + aI[2] * bc;
    bR[0] = 1.f; bI[0] = 0.f;
    bR[1] = aR[2] * aR[2] - aI[2] * aI[2];  bI[1] = 2.f * aR[2] * aI[2];
    bR[2] = bR[1] * bR[1] - bI[1] * bI[1];  bI[2] = 2.f * bR[1] * bI[1];
    bR[3] = bR[2] * bR[1] - bI[2] * bI[1];  bI[3] = bR[2] * bI[1] + bI[2] * bR[1];
    #pragma unroll
    for (int c = 0; c < 16; ++c) {
        int p = ((c & 3) << 2) | (c >> 2);
        float x0 = vr[p], y0 = vi[p];
        float x1 = x0 * aR[c & 3] - y0 * aI[c & 3];
        float y1 = x0 * aI[c & 3] + y0 * aR[c & 3];
        float x2 = x1 * bR[c >> 2] - y1 * bI[c >> 2];
        float y2 = x1 * bI[c >> 2] + y1 * bR[c >> 2];
        row[c ^ xorv] = make_float2(x2, y2);
    }
}

// ======================= main kernel: wave per pixel, 2 waves/block =========
// Identical per-thread code to the proven R4 kernel (145us, 56 VGPR); only
// the block geometry changed: 2 waves x 8KB = 16KB LDS/block -> 10 blocks/CU
// (20 waves/CU ceiling) instead of 32KB blocks needing the whole LDS pool.
// FFT1024 = FFT16(regs over a) -> *W1024^{tc} -> T1 -> FFT16(regs over e)
//           -> *W64^{fm} -> T2 -> FFT4(regs over f).  n=64a+b; b=4e+f;
//           k = c + 16m + 256p.
__global__ __launch_bounds__(128, 4)
void conv128(const float* __restrict__ x, const float4* __restrict__ uv,
             float2* __restrict__ out) {
    __shared__ float2 ldsAll[2 * HALF];
    const int tid = threadIdx.x;
    const int t   = tid & 63;
    const int wid = tid >> 6;
    float2* lds = ldsAll + (wid << 10);
    const size_t pix = ((size_t)blockIdx.x << 1) + wid;
    const float2* xp = reinterpret_cast<const float2*>(x) + pix * (size_t)HALF;

    float vr[16], vi[16];
    #pragma unroll
    for (int a = 0; a < 16; ++a) {
        float2 z = xp[(a << 6) + t];
        vr[a] = z.x; vi[a] = z.y;
    }

    // ---------------- forward ----------------
    fft16_ip<-1>(vr, vi);
    tw_store(vr, vi, lds + (t << 4), t & 15,
             (-6.283185307179586f / 1024.0f) * (float)t);          // T1 write
    __syncthreads();
    {
        const int f = t & 3, c = t >> 2;
        #pragma unroll
        for (int e = 0; e < 16; ++e) {                              // T1 read
            int row = (e << 2) + f;
            float2 z = lds[(row << 4) + (c ^ (row & 15))];
            vr[e] = z.x; vi[e] = z.y;
        }
        __syncthreads();
        fft16_ip<-1>(vr, vi);
        tw_store(vr, vi, lds + (t << 4), c,
                 (-6.283185307179586f / 64.0f) * (float)f);         // T2 write
    }
    __syncthreads();
    {
        const int q = t & 3, c = t >> 2;
        float dr[16], di[16];
        #pragma unroll
        for (int f = 0; f < 4; ++f) {
            #pragma unroll
            for (int s = 0; s < 4; ++s) {                           // T2 read
                int wrow = (c << 2) + f;
                float2 z = lds[(wrow << 4) + (((q << 2) + s) ^ c)];
                dr[f * 4 + s] = z.x; di[f * 4 + s] = z.y;
            }
        }
        __syncthreads();
        #pragma unroll
        for (int s = 0; s < 4; ++s) {                               // FFT4 fwd
            float ar = dr[0 + s],  ai = di[0 + s];
            float br = dr[4 + s],  bi = di[4 + s];
            float cr = dr[8 + s],  ci = di[8 + s];
            float er = dr[12 + s], ei = di[12 + s];
            float t0r = ar + cr, t0i = ai + ci;
            float t1r = ar - cr, t1i = ai - ci;
            float t2r = br + er, t2i = bi + ei;
            float t3r = br - er, t3i = bi - ei;
            int kb = c + (((q << 2) + s) << 4);
            lds[kb]       = make_float2(t0r + t2r, t0i + t2i);      // p=0
            lds[kb + 256] = make_float2(t1r + t3i, t1i - t3r);      // p=1 (S=-1)
            lds[kb + 512] = make_float2(t0r - t2r, t0i - t2i);      // p=2
            lds[kb + 768] = make_float2(t1r - t3i, t1i + t3r);      // p=3
        }
    }
    __syncthreads();

    // ------------- middle (rfft unpack * Wf * repack) ------------
    #pragma unroll
    for (int a = 0; a < 16; ++a) {
        int k = (a << 6) + t;
        float2 Za = lds[k];
        float2 Zm = lds[(HALF - k) & (HALF - 1)];
        float4 u  = uv[k];
        float Ar = Za.x + Zm.x, Ai = Za.y - Zm.y;
        float Br = Za.x - Zm.x, Bi = Za.y + Zm.y;
        vr[a] = Ar * u.x - Ai * u.y + Br * u.z - Bi * u.w;
        vi[a] = Ar * u.y + Ai * u.x + Br * u.w + Bi * u.z;
    }
    __syncthreads();

    // ---------------- inverse ----------------
    fft16_ip<1>(vr, vi);
    tw_store(vr, vi, lds + (t << 4), t & 15,
             (6.283185307179586f / 1024.0f) * (float)t);            // T4 write
    __syncthreads();
    {
        const int f = t & 3, c = t >> 2;
        #pragma unroll
        for (int e = 0; e < 16; ++e) {                              // T4 read
            int row = (e << 2) + f;
            float2 z = lds[(row << 4) + (c ^ (row & 15))];
            vr[e] = z.x; vi[e] = z.y;
        }
        __syncthreads();
        fft16_ip<1>(vr, vi);
        tw_store(vr, vi, lds + (t << 4), c,
                 (6.283185307179586f / 64.0f) * (float)f);          // T5 write
    }
    __syncthreads();
    {
        const int q = t & 3, c = t >> 2;
        float dr[16], di[16];
        #pragma unroll
        for (int f = 0; f < 4; ++f) {
            #pragma unroll
            for (int s = 0; s < 4; ++s) {                           // T5 read
                int wrow = (c << 2) + f;
                float2 z = lds[(wrow << 4) + (((q << 2) + s) ^ c)];
                dr[f * 4 + s] = z.x; di[f * 4 + s] = z.y;
            }
        }
        float2* op = out + pix * (size_t)(OUTD / 2);
        #pragma unroll
        for (int s = 0; s < 4; ++s) {                               // FFT4 inv
            float ar = dr[0 + s],  ai = di[0 + s];
            float br = dr[4 + s],  bi = di[4 + s];
            float cr = dr[8 + s],  ci = di[8 + s];
            float er = dr[12 + s], ei = di[12 + s];
            float t0r = ar + cr, t0i = ai + ci;
            float t1r = ar - cr, t1i = ai - ci;
            float t2r = br + er, t2i = bi + ei;
            float t3r = br - er, t3i = bi - ei;
            int nb = c + (((q << 2) + s) << 4);
            op[nb]       = make_float2(t0r + t2r, t0i + t2i);       // p=0
            op[nb + 256] = make_float2(t1r - t3i, t1i + t3r);       // p=1 (S=+1)
            op[nb + 512] = make_float2(t0r - t2r, t0i - t2i);       // p=2
            // p=3 (n >= 768) not stored
        }
    }
}

extern "C" void kernel_launch(void* const* d_in, const int* in_sizes, int n_in,
                              void* d_out, int out_size, void* d_ws, size_t ws_size,
                              hipStream_t stream) {
    const float* x  = (const float*)d_in[0];
    const float* w1 = (const float*)d_in[1];
    const float* w2 = (const float*)d_in[2];
    float2* out = (float2*)d_out;
    float4* uv  = (float4*)d_ws;          // 1024 float4 = 16 KB

    hipLaunchKernelGGL(uv_kernel, dim3(1), dim3(256), 0, stream, w1, w2, uv);
    hipLaunchKernelGGL(conv128, dim3(NPIX / 2), dim3(128), 0, stream, x, uv, out);
}

// Round 8
// 130.148 us; speedup vs baseline: 2.4488x; 1.0607x over previous
//
#include <hip/hip_runtime.h>
#include <math.h>

#define C_LEN 2048
#define HALF  1024
#define OUTD  1536
#define NPIX  32768
#define LDSW  1088   // per-wave float2 slice: 64 rows x 17 (pad) for T1/T4;
                     // flat [0,1024) reused by T2/FFT4/middle/T5

#define FENCE() __builtin_amdgcn_sched_barrier(0)

// ======================= uv precompute (unchanged, verified) ================
__device__ __forceinline__ int SWZ(int idx) { return idx ^ ((idx >> 5) & 31); }

template<int DIR>
__device__ void fft2048(float* r0, float* i0, float* r1, float* i1, int t) {
    float *sr = r0, *si = i0, *dr = r1, *di = i1;
    const float TW = (float)DIR * 6.283185307179586f / 2048.0f;
    const float FD = (float)DIR;
    __syncthreads();
    #pragma unroll
    for (int b = 0; b < 4; ++b) {
        int t2 = t + b * 256;
        float ar = sr[SWZ(t2)],        ai = si[SWZ(t2)];
        float br = sr[SWZ(t2 + 1024)], bi = si[SWZ(t2 + 1024)];
        float sn, cs;
        sincosf(TW * (float)t2, &sn, &cs);
        float vr = ar - br, vi = ai - bi;
        int w0 = 2 * t2;
        dr[SWZ(w0)]     = ar + br;
        di[SWZ(w0)]     = ai + bi;
        dr[SWZ(w0 + 1)] = cs * vr - sn * vi;
        di[SWZ(w0 + 1)] = cs * vi + sn * vr;
    }
    { float* tp; tp = sr; sr = dr; dr = tp; tp = si; si = di; di = tp; }
    #pragma unroll
    for (int m = 2; m <= 512; m *= 4) {
        __syncthreads();
        #pragma unroll
        for (int b = 0; b < 2; ++b) {
            int t2 = t + b * 256;
            int jm = t2 & ~(m - 1);
            float a0r = sr[SWZ(t2)],        a0i = si[SWZ(t2)];
            float a1r = sr[SWZ(t2 + 512)],  a1i = si[SWZ(t2 + 512)];
            float a2r = sr[SWZ(t2 + 1024)], a2i = si[SWZ(t2 + 1024)];
            float a3r = sr[SWZ(t2 + 1536)], a3i = si[SWZ(t2 + 1536)];
            float s0r = a0r + a2r, s0i = a0i + a2i;
            float d0r = a0r - a2r, d0i = a0i - a2i;
            float s1r = a1r + a3r, s1i = a1i + a3i;
            float d1r = a1r - a3r, d1i = a1i - a3i;
            float A0r = s0r + s1r, A0i = s0i + s1i;
            float A2r = s0r - s1r, A2i = s0i - s1i;
            float A1r = d0r - FD * d1i, A1i = d0i + FD * d1r;
            float A3r = d0r + FD * d1i, A3i = d0i - FD * d1r;
            float s1w, c1w;
            sincosf(TW * (float)jm, &s1w, &c1w);
            float c2w = c1w * c1w - s1w * s1w, s2w = 2.0f * c1w * s1w;
            float c3w = c1w * c2w - s1w * s2w, s3w = c1w * s2w + s1w * c2w;
            int wb = t2 + 3 * jm;
            dr[SWZ(wb)]         = A0r;
            di[SWZ(wb)]         = A0i;
            dr[SWZ(wb + m)]     = c1w * A1r - s1w * A1i;
            di[SWZ(wb + m)]     = c1w * A1i + s1w * A1r;
            dr[SWZ(wb + 2 * m)] = c2w * A2r - s2w * A2i;
            di[SWZ(wb + 2 * m)] = c2w * A2i + s2w * A2r;
            dr[SWZ(wb + 3 * m)] = c3w * A3r - s3w * A3i;
            di[SWZ(wb + 3 * m)] = c3w * A3i + s3w * A3r;
        }
        { float* tp; tp = sr; sr = dr; dr = tp; tp = si; si = di; di = tp; }
    }
    __syncthreads();
}

__global__ __launch_bounds__(256)
void uv_kernel(const float* __restrict__ w1, const float* __restrict__ w2,
               float4* __restrict__ uv) {
    __shared__ float r0[C_LEN], i0[C_LEN], r1[C_LEN], i1[C_LEN];
    int t = threadIdx.x;
    #pragma unroll
    for (int k = 0; k < 8; ++k) {
        int e = t + k * 256;
        r0[SWZ(e)] = w1[e] * w2[e];
        i0[SWZ(e)] = 0.0f;
    }
    fft2048<-1>(r0, i0, r1, i1, t);
    #pragma unroll
    for (int b = 0; b < 4; ++b) {
        int k = t + b * 256;
        float w1r = r0[SWZ(k)],        w1i = i0[SWZ(k)];
        float w2r = r0[SWZ(k + 1024)], w2i = i0[SWZ(k + 1024)];
        float Sr = (w1r + w2r) * (1.0f / 4096.0f);
        float Si = (w1i + w2i) * (1.0f / 4096.0f);
        float Dr = (w1r - w2r) * (1.0f / 4096.0f);
        float Di = (w1i - w2i) * (1.0f / 4096.0f);
        float sn, cs;
        sincosf((6.283185307179586f / 2048.0f) * (float)k, &sn, &cs);
        float Er = cs * Dr - sn * Di, Ei = cs * Di + sn * Dr;
        float Fr = cs * Dr + sn * Di, Fi = cs * Di - sn * Dr;
        uv[k] = make_float4(Sr - Ei, Si + Er, Sr + Fi, Si - Fr);
    }
}

// ======================= in-place register FFT16 ============================
__device__ __forceinline__ void cm(float& or_, float& oi_, float ar, float ai,
                                   float br, float bi) {
    or_ = ar * br - ai * bi;
    oi_ = ar * bi + ai * br;
}

// In-place 16-pt DFT (sign S). Output digit-swapped:
//   slot[4*(k&3) + (k>>2)] = X[k],  X[k] = sum_n x[n] e^{S*2*pi*i*n*k/16}
template<int S>
__device__ __forceinline__ void fft16_ip(float* xr, float* xi) {
    const float FS = (float)S;
    const float C1 = 0.9238795325112867f;
    const float S1 = 0.3826834323650898f;
    const float R2 = 0.7071067811865476f;
    #pragma unroll
    for (int n0 = 0; n0 < 4; ++n0) {
        float a0r = xr[n0],      a0i = xi[n0];
        float a1r = xr[n0 + 4],  a1i = xi[n0 + 4];
        float a2r = xr[n0 + 8],  a2i = xi[n0 + 8];
        float a3r = xr[n0 + 12], a3i = xi[n0 + 12];
        float t0r = a0r + a2r, t0i = a0i + a2i;
        float t1r = a0r - a2r, t1i = a0i - a2i;
        float t2r = a1r + a3r, t2i = a1i + a3i;
        float t3r = a1r - a3r, t3i = a1i - a3i;
        float y1r = t1r - FS * t3i, y1i = t1i + FS * t3r;
        float y2r = t0r - t2r,      y2i = t0i - t2i;
        float y3r = t1r + FS * t3i, y3i = t1i - FS * t3r;
        xr[n0] = t0r + t2r;  xi[n0] = t0i + t2i;
        if (n0 == 0) {
            xr[4]  = y1r; xi[4]  = y1i;
            xr[8]  = y2r; xi[8]  = y2i;
            xr[12] = y3r; xi[12] = y3i;
        } else if (n0 == 1) {
            cm(xr[5],  xi[5],  y1r, y1i, C1,  FS * S1);
            cm(xr[9],  xi[9],  y2r, y2i, R2,  FS * R2);
            cm(xr[13], xi[13], y3r, y3i, S1,  FS * C1);
        } else if (n0 == 2) {
            cm(xr[6],  xi[6],  y1r, y1i, R2,  FS * R2);
            xr[10] = -FS * y2i;  xi[10] = FS * y2r;
            cm(xr[14], xi[14], y3r, y3i, -R2, FS * R2);
        } else {
            cm(xr[7],  xi[7],  y1r, y1i, S1,  FS * C1);
            cm(xr[11], xi[11], y2r, y2i, -R2, FS * R2);
            cm(xr[15], xi[15], y3r, y3i, -C1, -FS * S1);
        }
    }
    #pragma unroll
    for (int k0 = 0; k0 < 4; ++k0) {
        float b0r = xr[4 * k0],     b0i = xi[4 * k0];
        float b1r = xr[4 * k0 + 1], b1i = xi[4 * k0 + 1];
        float b2r = xr[4 * k0 + 2], b2i = xi[4 * k0 + 2];
        float b3r = xr[4 * k0 + 3], b3i = xi[4 * k0 + 3];
        float t0r = b0r + b2r, t0i = b0i + b2i;
        float t1r = b0r - b2r, t1i = b0i - b2i;
        float t2r = b1r + b3r, t2i = b1i + b3i;
        float t3r = b1r - b3r, t3i = b1i - b3i;
        xr[4 * k0]     = t0r + t2r;      xi[4 * k0]     = t0i + t2i;
        xr[4 * k0 + 1] = t1r - FS * t3i; xi[4 * k0 + 1] = t1i + FS * t3r;
        xr[4 * k0 + 2] = t0r - t2r;      xi[4 * k0 + 2] = t0i - t2i;
        xr[4 * k0 + 3] = t1r + FS * t3i; xi[4 * k0 + 3] = t1i - FS * t3r;
    }
}

// Fused twiddle (w^c = e^{i*c*th}) + transposed LDS store.
// Reads logical element c from digit-swapped slot, writes row[c ^ xorv].
// (xorv=0 for the padded T1/T4 layout -> pure imm-offset stores.)
__device__ __forceinline__ void tw_store(const float* vr, const float* vi,
                                         float2* row, int xorv, float th) {
    float bs, bc;
    __sincosf(th, &bs, &bc);
    float aR[4], aI[4], bR[4], bI[4];
    aR[0] = 1.f; aI[0] = 0.f;
    aR[1] = bc;  aI[1] = bs;
    aR[2] = bc * bc - bs * bs;          aI[2] = 2.f * bc * bs;
    aR[3] = aR[2] * bc - aI[2] * bs;    aI[3] = aR[2] * bs + aI[2] * bc;
    bR[0] = 1.f; bI[0] = 0.f;
    bR[1] = aR[2] * aR[2] - aI[2] * aI[2];  bI[1] = 2.f * aR[2] * aI[2];
    bR[2] = bR[1] * bR[1] - bI[1] * bI[1];  bI[2] = 2.f * bR[1] * bI[1];
    bR[3] = bR[2] * bR[1] - bI[2] * bI[1];  bI[3] = bR[2] * bI[1] + bI[2] * bR[1];
    #pragma unroll
    for (int c = 0; c < 16; ++c) {
        int p = ((c & 3) << 2) | (c >> 2);
        float x0 = vr[p], y0 = vi[p];
        float x1 = x0 * aR[c & 3] - y0 * aI[c & 3];
        float y1 = x0 * aI[c & 3] + y0 * aR[c & 3];
        float x2 = x1 * bR[c >> 2] - y1 * bI[c >> 2];
        float y2 = x1 * bI[c >> 2] + y1 * bR[c >> 2];
        row[c ^ xorv] = make_float2(x2, y2);
    }
}

// ======================= main kernel: wave per pixel, 2 waves/block =========
// Per-thread algorithm identical to the proven R4/R7 kernel. Changes:
//  * T1/T4 transposes use a padded row layout (row r at r*17 float2):
//    bank-conflict floor on both sides with NO xor -> base + imm addressing.
//  * T2/T5/FFT4/middle keep the proven unpadded+XOR addressing in the flat
//    [0,1024) region of the same slice (phases fully rewrite the buffer).
//  * All __syncthreads() replaced by sched_barrier(0): the 2 waves own
//    disjoint LDS slices, so barriers were cross-wave lockstep only (R5
//    proved correctness of barrier-free; fences keep live ranges short).
__global__ __launch_bounds__(128, 4)
void conv128(const float* __restrict__ x, const float4* __restrict__ uv,
             float2* __restrict__ out) {
    __shared__ float2 ldsAll[2 * LDSW];
    const int tid = threadIdx.x;
    const int t   = tid & 63;
    const int wid = tid >> 6;
    float2* lds = ldsAll + wid * LDSW;
    const size_t pix = ((size_t)blockIdx.x << 1) + wid;
    const float2* xp = reinterpret_cast<const float2*>(x) + pix * (size_t)HALF;

    float vr[16], vi[16];
    #pragma unroll
    for (int a = 0; a < 16; ++a) {
        float2 z = xp[(a << 6) + t];
        vr[a] = z.x; vi[a] = z.y;
    }

    // ---------------- forward ----------------
    fft16_ip<-1>(vr, vi);
    tw_store(vr, vi, lds + t * 17, 0,
             (-6.283185307179586f / 1024.0f) * (float)t);          // T1w (pad)
    FENCE();
    {
        const int f = t & 3, c = t >> 2;
        const float2* rp = lds + f * 17 + c;                        // T1r (pad)
        #pragma unroll
        for (int e = 0; e < 16; ++e) {
            float2 z = rp[e * 68];                                  // (4e)*17
            vr[e] = z.x; vi[e] = z.y;
        }
        FENCE();
        fft16_ip<-1>(vr, vi);
        tw_store(vr, vi, lds + (t << 4), c,
                 (-6.283185307179586f / 64.0f) * (float)f);         // T2w (xor)
    }
    FENCE();
    {
        const int q = t & 3, c = t >> 2;
        float dr[16], di[16];
        #pragma unroll
        for (int f = 0; f < 4; ++f) {
            #pragma unroll
            for (int s = 0; s < 4; ++s) {                           // T2r (xor)
                int wrow = (c << 2) + f;
                float2 z = lds[(wrow << 4) + (((q << 2) + s) ^ c)];
                dr[f * 4 + s] = z.x; di[f * 4 + s] = z.y;
            }
        }
        FENCE();
        #pragma unroll
        for (int s = 0; s < 4; ++s) {                               // FFT4 fwd
            float ar = dr[0 + s],  ai = di[0 + s];
            float br = dr[4 + s],  bi = di[4 + s];
            float cr = dr[8 + s],  ci = di[8 + s];
            float er = dr[12 + s], ei = di[12 + s];
            float t0r = ar + cr, t0i = ai + ci;
            float t1r = ar - cr, t1i = ai - ci;
            float t2r = br + er, t2i = bi + ei;
            float t3r = br - er, t3i = bi - ei;
            int kb = c + (q << 6) + (s << 4);
            lds[kb]       = make_float2(t0r + t2r, t0i + t2i);      // p=0
            lds[kb + 256] = make_float2(t1r + t3i, t1i - t3r);      // p=1 (S=-1)
            lds[kb + 512] = make_float2(t0r - t2r, t0i - t2i);      // p=2
            lds[kb + 768] = make_float2(t1r - t3i, t1i + t3r);      // p=3
        }
    }
    FENCE();

    // ------------- middle (rfft unpack * Wf * repack) ------------
    #pragma unroll
    for (int a = 0; a < 16; ++a) {
        int k = (a << 6) + t;
        float2 Za = lds[k];
        float2 Zm = lds[(HALF - k) & (HALF - 1)];
        float4 u  = uv[k];
        float Ar = Za.x + Zm.x, Ai = Za.y - Zm.y;
        float Br = Za.x - Zm.x, Bi = Za.y + Zm.y;
        vr[a] = Ar * u.x - Ai * u.y + Br * u.z - Bi * u.w;
        vi[a] = Ar * u.y + Ai * u.x + Br * u.w + Bi * u.z;
    }
    FENCE();

    // ---------------- inverse ----------------
    fft16_ip<1>(vr, vi);
    tw_store(vr, vi, lds + t * 17, 0,
             (6.283185307179586f / 1024.0f) * (float)t);            // T4w (pad)
    FENCE();
    {
        const int f = t & 3, c = t >> 2;
        const float2* rp = lds + f * 17 + c;                        // T4r (pad)
        #pragma unroll
        for (int e = 0; e < 16; ++e) {
            float2 z = rp[e * 68];
            vr[e] = z.x; vi[e] = z.y;
        }
        FENCE();
        fft16_ip<1>(vr, vi);
        tw_store(vr, vi, lds + (t << 4), c,
                 (6.283185307179586f / 64.0f) * (float)f);          // T5w (xor)
    }
    FENCE();
    {
        const int q = t & 3, c = t >> 2;
        float dr[16], di[16];
        #pragma unroll
        for (int f = 0; f < 4; ++f) {
            #pragma unroll
            for (int s = 0; s < 4; ++s) {                           // T5r (xor)
                int wrow = (c << 2) + f;
                float2 z = lds[(wrow << 4) + (((q << 2) + s) ^ c)];
                dr[f * 4 + s] = z.x; di[f * 4 + s] = z.y;
            }
        }
        float2* op = out + pix * (size_t)(OUTD / 2);
        #pragma unroll
        for (int s = 0; s < 4; ++s) {                               // FFT4 inv
            float ar = dr[0 + s],  ai = di[0 + s];
            float br = dr[4 + s],  bi = di[4 + s];
            float cr = dr[8 + s],  ci = di[8 + s];
            float er = dr[12 + s], ei = di[12 + s];
            float t0r = ar + cr, t0i = ai + ci;
            float t1r = ar - cr, t1i = ai - ci;
            float t2r = br + er, t2i = bi + ei;
            float t3r = br - er, t3i = bi - ei;
            int nb = c + (q << 6) + (s << 4);
            op[nb]       = make_float2(t0r + t2r, t0i + t2i);       // p=0
            op[nb + 256] = make_float2(t1r - t3i, t1i + t3r);       // p=1 (S=+1)
            op[nb + 512] = make_float2(t0r - t2r, t0i - t2i);       // p=2
            // p=3 (n >= 768) not stored
        }
    }
}

extern "C" void kernel_launch(void* const* d_in, const int* in_sizes, int n_in,
                              void* d_out, int out_size, void* d_ws, size_t ws_size,
                              hipStream_t stream) {
    const float* x  = (const float*)d_in[0];
    const float* w1 = (const float*)d_in[1];
    const float* w2 = (const float*)d_in[2];
    float2* out = (float2*)d_out;
    float4* uv  = (float4*)d_ws;          // 1024 float4 = 16 KB

    hipLaunchKernelGGL(uv_kernel, dim3(1), dim3(256), 0, stream, w1, w2, uv);
    hipLaunchKernelGGL(conv128, dim3(NPIX / 2), dim3(128), 0, stream, x, uv, out);
}

// Round 9
// 128.602 us; speedup vs baseline: 2.4782x; 1.0120x over previous
//
#include <hip/hip_runtime.h>
#include <math.h>

#define C_LEN 2048
#define HALF  1024
#define OUTD  1536
#define NPIX  32768
#define LDSW  1088   // per-block float4 slice: 64 rows x 17 (pad) for T1/T4;
                     // flat [0,1024) reused by T2/FFT4/middle/T5
                     // float4 slot = (A.re, A.im, B.re, B.im)

#define FENCE() __builtin_amdgcn_sched_barrier(0)

// ======================= uv precompute (unchanged, verified) ================
__device__ __forceinline__ int SWZ(int idx) { return idx ^ ((idx >> 5) & 31); }

template<int DIR>
__device__ void fft2048(float* r0, float* i0, float* r1, float* i1, int t) {
    float *sr = r0, *si = i0, *dr = r1, *di = i1;
    const float TW = (float)DIR * 6.283185307179586f / 2048.0f;
    const float FD = (float)DIR;
    __syncthreads();
    #pragma unroll
    for (int b = 0; b < 4; ++b) {
        int t2 = t + b * 256;
        float ar = sr[SWZ(t2)],        ai = si[SWZ(t2)];
        float br = sr[SWZ(t2 + 1024)], bi = si[SWZ(t2 + 1024)];
        float sn, cs;
        sincosf(TW * (float)t2, &sn, &cs);
        float vr = ar - br, vi = ai - bi;
        int w0 = 2 * t2;
        dr[SWZ(w0)]     = ar + br;
        di[SWZ(w0)]     = ai + bi;
        dr[SWZ(w0 + 1)] = cs * vr - sn * vi;
        di[SWZ(w0 + 1)] = cs * vi + sn * vr;
    }
    { float* tp; tp = sr; sr = dr; dr = tp; tp = si; si = di; di = tp; }
    #pragma unroll
    for (int m = 2; m <= 512; m *= 4) {
        __syncthreads();
        #pragma unroll
        for (int b = 0; b < 2; ++b) {
            int t2 = t + b * 256;
            int jm = t2 & ~(m - 1);
            float a0r = sr[SWZ(t2)],        a0i = si[SWZ(t2)];
            float a1r = sr[SWZ(t2 + 512)],  a1i = si[SWZ(t2 + 512)];
            float a2r = sr[SWZ(t2 + 1024)], a2i = si[SWZ(t2 + 1024)];
            float a3r = sr[SWZ(t2 + 1536)], a3i = si[SWZ(t2 + 1536)];
            float s0r = a0r + a2r, s0i = a0i + a2i;
            float d0r = a0r - a2r, d0i = a0i - a2i;
            float s1r = a1r + a3r, s1i = a1i + a3i;
            float d1r = a1r - a3r, d1i = a1i - a3i;
            float A0r = s0r + s1r, A0i = s0i + s1i;
            float A2r = s0r - s1r, A2i = s0i - s1i;
            float A1r = d0r - FD * d1i, A1i = d0i + FD * d1r;
            float A3r = d0r + FD * d1i, A3i = d0i - FD * d1r;
            float s1w, c1w;
            sincosf(TW * (float)jm, &s1w, &c1w);
            float c2w = c1w * c1w - s1w * s1w, s2w = 2.0f * c1w * s1w;
            float c3w = c1w * c2w - s1w * s2w, s3w = c1w * s2w + s1w * c2w;
            int wb = t2 + 3 * jm;
            dr[SWZ(wb)]         = A0r;
            di[SWZ(wb)]         = A0i;
            dr[SWZ(wb + m)]     = c1w * A1r - s1w * A1i;
            di[SWZ(wb + m)]     = c1w * A1i + s1w * A1r;
            dr[SWZ(wb + 2 * m)] = c2w * A2r - s2w * A2i;
            di[SWZ(wb + 2 * m)] = c2w * A2i + s2w * A2r;
            dr[SWZ(wb + 3 * m)] = c3w * A3r - s3w * A3i;
            di[SWZ(wb + 3 * m)] = c3w * A3i + s3w * A3r;
        }
        { float* tp; tp = sr; sr = dr; dr = tp; tp = si; si = di; di = tp; }
    }
    __syncthreads();
}

__global__ __launch_bounds__(256)
void uv_kernel(const float* __restrict__ w1, const float* __restrict__ w2,
               float4* __restrict__ uv) {
    __shared__ float r0[C_LEN], i0[C_LEN], r1[C_LEN], i1[C_LEN];
    int t = threadIdx.x;
    #pragma unroll
    for (int k = 0; k < 8; ++k) {
        int e = t + k * 256;
        r0[SWZ(e)] = w1[e] * w2[e];
        i0[SWZ(e)] = 0.0f;
    }
    fft2048<-1>(r0, i0, r1, i1, t);
    #pragma unroll
    for (int b = 0; b < 4; ++b) {
        int k = t + b * 256;
        float w1r = r0[SWZ(k)],        w1i = i0[SWZ(k)];
        float w2r = r0[SWZ(k + 1024)], w2i = i0[SWZ(k + 1024)];
        float Sr = (w1r + w2r) * (1.0f / 4096.0f);
        float Si = (w1i + w2i) * (1.0f / 4096.0f);
        float Dr = (w1r - w2r) * (1.0f / 4096.0f);
        float Di = (w1i - w2i) * (1.0f / 4096.0f);
        float sn, cs;
        sincosf((6.283185307179586f / 2048.0f) * (float)k, &sn, &cs);
        float Er = cs * Dr - sn * Di, Ei = cs * Di + sn * Dr;
        float Fr = cs * Dr + sn * Di, Fi = cs * Di - sn * Dr;
        uv[k] = make_float4(Sr - Ei, Si + Er, Sr + Fi, Si - Fr);
    }
}

// ======================= in-place register FFT16 ============================
__device__ __forceinline__ void cm(float& or_, float& oi_, float ar, float ai,
                                   float br, float bi) {
    or_ = ar * br - ai * bi;
    oi_ = ar * bi + ai * br;
}

// In-place 16-pt DFT (sign S). Output digit-swapped:
//   slot[4*(k&3) + (k>>2)] = X[k],  X[k] = sum_n x[n] e^{S*2*pi*i*n*k/16}
template<int S>
__device__ __forceinline__ void fft16_ip(float* xr, float* xi) {
    const float FS = (float)S;
    const float C1 = 0.9238795325112867f;
    const float S1 = 0.3826834323650898f;
    const float R2 = 0.7071067811865476f;
    #pragma unroll
    for (int n0 = 0; n0 < 4; ++n0) {
        float a0r = xr[n0],      a0i = xi[n0];
        float a1r = xr[n0 + 4],  a1i = xi[n0 + 4];
        float a2r = xr[n0 + 8],  a2i = xi[n0 + 8];
        float a3r = xr[n0 + 12], a3i = xi[n0 + 12];
        float t0r = a0r + a2r, t0i = a0i + a2i;
        float t1r = a0r - a2r, t1i = a0i - a2i;
        float t2r = a1r + a3r, t2i = a1i + a3i;
        float t3r = a1r - a3r, t3i = a1i - a3i;
        float y1r = t1r - FS * t3i, y1i = t1i + FS * t3r;
        float y2r = t0r - t2r,      y2i = t0i - t2i;
        float y3r = t1r + FS * t3i, y3i = t1i - FS * t3r;
        xr[n0] = t0r + t2r;  xi[n0] = t0i + t2i;
        if (n0 == 0) {
            xr[4]  = y1r; xi[4]  = y1i;
            xr[8]  = y2r; xi[8]  = y2i;
            xr[12] = y3r; xi[12] = y3i;
        } else if (n0 == 1) {
            cm(xr[5],  xi[5],  y1r, y1i, C1,  FS * S1);
            cm(xr[9],  xi[9],  y2r, y2i, R2,  FS * R2);
            cm(xr[13], xi[13], y3r, y3i, S1,  FS * C1);
        } else if (n0 == 2) {
            cm(xr[6],  xi[6],  y1r, y1i, R2,  FS * R2);
            xr[10] = -FS * y2i;  xi[10] = FS * y2r;
            cm(xr[14], xi[14], y3r, y3i, -R2, FS * R2);
        } else {
            cm(xr[7],  xi[7],  y1r, y1i, S1,  FS * C1);
            cm(xr[11], xi[11], y2r, y2i, -R2, FS * R2);
            cm(xr[15], xi[15], y3r, y3i, -C1, -FS * S1);
        }
    }
    #pragma unroll
    for (int k0 = 0; k0 < 4; ++k0) {
        float b0r = xr[4 * k0],     b0i = xi[4 * k0];
        float b1r = xr[4 * k0 + 1], b1i = xi[4 * k0 + 1];
        float b2r = xr[4 * k0 + 2], b2i = xi[4 * k0 + 2];
        float b3r = xr[4 * k0 + 3], b3i = xi[4 * k0 + 3];
        float t0r = b0r + b2r, t0i = b0i + b2i;
        float t1r = b0r - b2r, t1i = b0i - b2i;
        float t2r = b1r + b3r, t2i = b1i + b3i;
        float t3r = b1r - b3r, t3i = b1i - b3i;
        xr[4 * k0]     = t0r + t2r;      xi[4 * k0]     = t0i + t2i;
        xr[4 * k0 + 1] = t1r - FS * t3i; xi[4 * k0 + 1] = t1i + FS * t3r;
        xr[4 * k0 + 2] = t0r - t2r;      xi[4 * k0 + 2] = t0i - t2i;
        xr[4 * k0 + 3] = t1r + FS * t3i; xi[4 * k0 + 3] = t1i - FS * t3r;
    }
}

// Fused twiddle + transposed LDS store, TWO pixels (A,B) sharing the twiddle
// recurrence. w^c = e^{i*c*th} combined once; applied to both pixels; stored
// as float4 (A.re, A.im, B.re, B.im) at row[c ^ xorv]. Reads digit-swapped
// slot p.
__device__ __forceinline__ void tw_store2(const float* vrA, const float* viA,
                                          const float* vrB, const float* viB,
                                          float4* row, int xorv, float th) {
    float bs, bc;
    __sincosf(th, &bs, &bc);
    float aR[4], aI[4], bR[4], bI[4];
    aR[0] = 1.f; aI[0] = 0.f;
    aR[1] = bc;  aI[1] = bs;
    aR[2] = bc * bc - bs * bs;          aI[2] = 2.f * bc * bs;
    aR[3] = aR[2] * bc - aI[2] * bs;    aI[3] = aR[2] * bs + aI[2] * bc;
    bR[0] = 1.f; bI[0] = 0.f;
    bR[1] = aR[2] * aR[2] - aI[2] * aI[2];  bI[1] = 2.f * aR[2] * aI[2];
    bR[2] = bR[1] * bR[1] - bI[1] * bI[1];  bI[2] = 2.f * bR[1] * bI[1];
    bR[3] = bR[2] * bR[1] - bI[2] * bI[1];  bI[3] = bR[2] * bI[1] + bI[2] * bR[1];
    #pragma unroll
    for (int c = 0; c < 16; ++c) {
        int p = ((c & 3) << 2) | (c >> 2);
        float wr = aR[c & 3] * bR[c >> 2] - aI[c & 3] * bI[c >> 2];
        float wi = aR[c & 3] * bI[c >> 2] + aI[c & 3] * bR[c >> 2];
        float xA = vrA[p] * wr - viA[p] * wi;
        float yA = vrA[p] * wi + viA[p] * wr;
        float xB = vrB[p] * wr - viB[p] * wi;
        float yB = vrB[p] * wi + viB[p] * wr;
        row[c ^ xorv] = make_float4(xA, yA, xB, yB);
    }
}

// ======================= main kernel: 2 pixels per wave =====================
// One 64-thread block = one wave = pixels (2*bid, 2*bid+1) interleaved in a
// single float4 LDS slice. Same index algebra as the verified R8 kernel;
// float2->float4 doubles payload per LDS op (b64->b128, all patterns at the
// 8-dword/bank wave64 floor) and the two dependence chains hide each other's
// latency. Twiddle recurrence, sincos and uv loads shared between pixels.
__global__ __launch_bounds__(64, 2)
void conv64x2(const float* __restrict__ x, const float4* __restrict__ uv,
              float2* __restrict__ out) {
    __shared__ float4 lds[LDSW];
    const int t = threadIdx.x;
    const size_t pixA = (size_t)blockIdx.x << 1;
    const float2* xpA = reinterpret_cast<const float2*>(x) + pixA * (size_t)HALF;
    const float2* xpB = xpA + HALF;

    float vrA[16], viA[16], vrB[16], viB[16];
    #pragma unroll
    for (int a = 0; a < 16; ++a) {
        float2 zA = xpA[(a << 6) + t];
        float2 zB = xpB[(a << 6) + t];
        vrA[a] = zA.x; viA[a] = zA.y;
        vrB[a] = zB.x; viB[a] = zB.y;
    }

    // ---------------- forward ----------------
    fft16_ip<-1>(vrA, viA);
    fft16_ip<-1>(vrB, viB);
    tw_store2(vrA, viA, vrB, viB, lds + t * 17, 0,
              (-6.283185307179586f / 1024.0f) * (float)t);          // T1w (pad)
    FENCE();
    {
        const int f = t & 3, c = t >> 2;
        const float4* rp = lds + f * 17 + c;                        // T1r (pad)
        #pragma unroll
        for (int e = 0; e < 16; ++e) {
            float4 z = rp[e * 68];                                  // (4e)*17
            vrA[e] = z.x; viA[e] = z.y; vrB[e] = z.z; viB[e] = z.w;
        }
        FENCE();
        fft16_ip<-1>(vrA, viA);
        fft16_ip<-1>(vrB, viB);
        tw_store2(vrA, viA, vrB, viB, lds + (t << 4), c,
                  (-6.283185307179586f / 64.0f) * (float)f);        // T2w (xor)
    }
    FENCE();
    {
        const int q = t & 3, c = t >> 2;
        float drA[16], diA[16], drB[16], diB[16];
        #pragma unroll
        for (int f2 = 0; f2 < 4; ++f2) {
            #pragma unroll
            for (int s = 0; s < 4; ++s) {                           // T2r (xor)
                int wrow = (c << 2) + f2;
                float4 z = lds[(wrow << 4) + (((q << 2) + s) ^ c)];
                drA[f2 * 4 + s] = z.x; diA[f2 * 4 + s] = z.y;
                drB[f2 * 4 + s] = z.z; diB[f2 * 4 + s] = z.w;
            }
        }
        FENCE();
        #pragma unroll
        for (int s = 0; s < 4; ++s) {                               // FFT4 fwd
            int kb = c + (q << 6) + (s << 4);
            {   // pixel A
                float ar = drA[0 + s],  ai = diA[0 + s];
                float br = drA[4 + s],  bi = diA[4 + s];
                float cr = drA[8 + s],  ci = diA[8 + s];
                float er = drA[12 + s], ei = diA[12 + s];
                float t0r = ar + cr, t0i = ai + ci;
                float t1r = ar - cr, t1i = ai - ci;
                float t2r = br + er, t2i = bi + ei;
                float t3r = br - er, t3i = bi - ei;
                float Br = drB[0 + s],  Bi = diB[0 + s];
                float Cr = drB[4 + s],  Ci = diB[4 + s];
                float Dr = drB[8 + s],  Di = diB[8 + s];
                float Er = drB[12 + s], Ei = diB[12 + s];
                float u0r = Br + Dr, u0i = Bi + Di;
                float u1r = Br - Dr, u1i = Bi - Di;
                float u2r = Cr + Er, u2i = Ci + Ei;
                float u3r = Cr - Er, u3i = Ci - Ei;
                lds[kb]       = make_float4(t0r + t2r, t0i + t2i,
                                            u0r + u2r, u0i + u2i);  // p=0
                lds[kb + 256] = make_float4(t1r + t3i, t1i - t3r,
                                            u1r + u3i, u1i - u3r);  // p=1 (S=-1)
                lds[kb + 512] = make_float4(t0r - t2r, t0i - t2i,
                                            u0r - u2r, u0i - u2i);  // p=2
                lds[kb + 768] = make_float4(t1r - t3i, t1i + t3r,
                                            u1r - u3i, u1i + u3r);  // p=3
            }
        }
    }
    FENCE();

    // ------------- middle (rfft unpack * Wf * repack), uv shared ------------
    #pragma unroll
    for (int a = 0; a < 16; ++a) {
        int k = (a << 6) + t;
        float4 Za = lds[k];
        float4 Zm = lds[(HALF - k) & (HALF - 1)];
        float4 u  = uv[k];
        {
            float Ar = Za.x + Zm.x, Ai = Za.y - Zm.y;
            float Br = Za.x - Zm.x, Bi = Za.y + Zm.y;
            vrA[a] = Ar * u.x - Ai * u.y + Br * u.z - Bi * u.w;
            viA[a] = Ar * u.y + Ai * u.x + Br * u.w + Bi * u.z;
        }
        {
            float Ar = Za.z + Zm.z, Ai = Za.w - Zm.w;
            float Br = Za.z - Zm.z, Bi = Za.w + Zm.w;
            vrB[a] = Ar * u.x - Ai * u.y + Br * u.z - Bi * u.w;
            viB[a] = Ar * u.y + Ai * u.x + Br * u.w + Bi * u.z;
        }
    }
    FENCE();

    // ---------------- inverse ----------------
    fft16_ip<1>(vrA, viA);
    fft16_ip<1>(vrB, viB);
    tw_store2(vrA, viA, vrB, viB, lds + t * 17, 0,
              (6.283185307179586f / 1024.0f) * (float)t);           // T4w (pad)
    FENCE();
    {
        const int f = t & 3, c = t >> 2;
        const float4* rp = lds + f * 17 + c;                        // T4r (pad)
        #pragma unroll
        for (int e = 0; e < 16; ++e) {
            float4 z = rp[e * 68];
            vrA[e] = z.x; viA[e] = z.y; vrB[e] = z.z; viB[e] = z.w;
        }
        FENCE();
        fft16_ip<1>(vrA, viA);
        fft16_ip<1>(vrB, viB);
        tw_store2(vrA, viA, vrB, viB, lds + (t << 4), c,
                  (6.283185307179586f / 64.0f) * (float)f);         // T5w (xor)
    }
    FENCE();
    {
        const int q = t & 3, c = t >> 2;
        float drA[16], diA[16], drB[16], diB[16];
        #pragma unroll
        for (int f2 = 0; f2 < 4; ++f2) {
            #pragma unroll
            for (int s = 0; s < 4; ++s) {                           // T5r (xor)
                int wrow = (c << 2) + f2;
                float4 z = lds[(wrow << 4) + (((q << 2) + s) ^ c)];
                drA[f2 * 4 + s] = z.x; diA[f2 * 4 + s] = z.y;
                drB[f2 * 4 + s] = z.z; diB[f2 * 4 + s] = z.w;
            }
        }
        float2* opA = out + pixA * (size_t)(OUTD / 2);
        float2* opB = opA + (OUTD / 2);
        #pragma unroll
        for (int s = 0; s < 4; ++s) {                               // FFT4 inv
            int nb = c + (q << 6) + (s << 4);
            {   // pixel A
                float ar = drA[0 + s],  ai = diA[0 + s];
                float br = drA[4 + s],  bi = diA[4 + s];
                float cr = drA[8 + s],  ci = diA[8 + s];
                float er = drA[12 + s], ei = diA[12 + s];
                float t0r = ar + cr, t0i = ai + ci;
                float t1r = ar - cr, t1i = ai - ci;
                float t2r = br + er, t2i = bi + ei;
                float t3r = br - er, t3i = bi - ei;
                opA[nb]       = make_float2(t0r + t2r, t0i + t2i);  // p=0
                opA[nb + 256] = make_float2(t1r - t3i, t1i + t3r);  // p=1 (S=+1)
                opA[nb + 512] = make_float2(t0r - t2r, t0i - t2i);  // p=2
            }
            {   // pixel B
                float ar = drB[0 + s],  ai = diB[0 + s];
                float br = drB[4 + s],  bi = diB[4 + s];
                float cr = drB[8 + s],  ci = diB[8 + s];
                float er = drB[12 + s], ei = diB[12 + s];
                float t0r = ar + cr, t0i = ai + ci;
                float t1r = ar - cr, t1i = ai - ci;
                float t2r = br + er, t2i = bi + ei;
                float t3r = br - er, t3i = bi - ei;
                opB[nb]       = make_float2(t0r + t2r, t0i + t2i);  // p=0
                opB[nb + 256] = make_float2(t1r - t3i, t1i + t3r);  // p=1 (S=+1)
                opB[nb + 512] = make_float2(t0r - t2r, t0i - t2i);  // p=2
            }
            // p=3 (n >= 768) not stored
        }
    }
}

extern "C" void kernel_launch(void* const* d_in, const int* in_sizes, int n_in,
                              void* d_out, int out_size, void* d_ws, size_t ws_size,
                              hipStream_t stream) {
    const float* x  = (const float*)d_in[0];
    const float* w1 = (const float*)d_in[1];
    const float* w2 = (const float*)d_in[2];
    float2* out = (float2*)d_out;
    float4* uv  = (float4*)d_ws;          // 1024 float4 = 16 KB

    hipLaunchKernelGGL(uv_kernel, dim3(1), dim3(256), 0, stream, w1, w2, uv);
    hipLaunchKernelGGL(conv64x2, dim3(NPIX / 2), dim3(64), 0, stream, x, uv, out);
}